// Round 5
// baseline (345.429 us; speedup 1.0000x reference)
//
#include <hip/hip_runtime.h>
#include <hip/hip_bf16.h>
#include <hip/hip_fp16.h>
#include <math.h>

constexpr int N_NODES = 50000;
constexpr int N_EDGES = 850000;
constexpr int HDIM = 128;   // H*D
constexpr int AGG_BLOCKS = N_NODES / 8;  // 6250
constexpr int BN_BUCKETS = 16;

typedef _Float16 f16x8 __attribute__((ext_vector_type(8)));
typedef float f32x4 __attribute__((ext_vector_type(4)));

// v_fma_mix_f32: acc += f16(lo/hi of pk) * w   (exact f16->f32 convert inside FMA)
#define FMAMIX_LO(acc, pk, w) \
    asm("v_fma_mix_f32 %0, %1, %2, %0 op_sel:[0,0,0] op_sel_hi:[1,0,0]" \
        : "+v"(acc) : "v"(pk), "v"(w))
#define FMAMIX_HI(acc, pk, w) \
    asm("v_fma_mix_f32 %0, %1, %2, %0 op_sel:[1,0,0] op_sel_hi:[1,0,0]" \
        : "+v"(acc) : "v"(pk), "v"(w))

__device__ __forceinline__ float elu1(float t) {
    return (t > 0.f) ? t : (__expf(t) - 1.f);
}

// ---------------- CSR build: two-phase bucket sort ----------------
constexpr int NB2 = 128;                                // buckets
constexpr int RANGE2 = (N_NODES + NB2 - 1) / NB2;       // 391 nodes/bucket
constexpr int CAP = 8192;                               // bucket capacity (avg 6641)
constexpr int CHUNK = 8192;                             // edges per phase-A block
constexpr int GA = (N_EDGES + CHUNK - 1) / CHUNK;       // 104 blocks

__global__ void k_partA(const int* __restrict__ src, const int* __restrict__ dst,
                        int* __restrict__ g_cursor, unsigned* __restrict__ bucket) {
    __shared__ int hist[NB2];
    int tid = threadIdx.x;
    int e0 = blockIdx.x * CHUNK;
    int e1 = min(e0 + CHUNK, N_EDGES);
    if (tid < NB2) hist[tid] = 0;
    __syncthreads();
    for (int i = e0 + tid; i < e1; i += 1024) {
        int d = dst[i];
        atomicAdd(&hist[d / RANGE2], 1);
    }
    __syncthreads();
    int base = 0;
    if (tid < NB2) base = atomicAdd(&g_cursor[tid], hist[tid]);
    __syncthreads();
    if (tid < NB2) hist[tid] = base;
    __syncthreads();
    for (int i = e0 + tid; i < e1; i += 1024) {
        int d = dst[i];
        int s = src[i];
        int b = d / RANGE2;
        int p = atomicAdd(&hist[b], 1);
        bucket[b * CAP + p] = (unsigned)s | ((unsigned)(d - b * RANGE2) << 16);
    }
}

__global__ void k_partB(const unsigned* __restrict__ bucket, const int* __restrict__ cnts,
                        int* __restrict__ rowstart, int* __restrict__ esrc) {
    __shared__ int cnt_s[NB2];
    __shared__ int hist[RANGE2];
    __shared__ int lcur[RANGE2];
    __shared__ int wsum[7];
    int b = blockIdx.x, tid = threadIdx.x;
    int lo = b * RANGE2;
    int myCount = cnts[b];
    if (tid < NB2) cnt_s[tid] = cnts[tid];
    __syncthreads();
    for (int off = 1; off < NB2; off <<= 1) {
        int t = (tid < NB2 && tid >= off) ? cnt_s[tid - off] : 0;
        __syncthreads();
        if (tid < NB2) cnt_s[tid] += t;
        __syncthreads();
    }
    int base = cnt_s[b] - myCount;
    for (int j = tid; j < RANGE2; j += 1024) hist[j] = 0;
    __syncthreads();
    const unsigned* my = bucket + (size_t)b * CAP;
    for (int i = tid; i < myCount; i += 1024) atomicAdd(&hist[my[i] >> 16], 1);
    __syncthreads();
    int v = 0;
    if (tid < 448) v = (tid < RANGE2) ? hist[tid] : 0;
    int inc = v;
    int lane = tid & 63;
#pragma unroll
    for (int off = 1; off < 64; off <<= 1) {
        int t = __shfl_up(inc, off, 64);
        if (lane >= off) inc += t;
    }
    if (tid < 448 && lane == 63) wsum[tid >> 6] = inc;
    __syncthreads();
    if (tid < RANGE2) {
        int woff = 0;
        for (int w = 0; w < (tid >> 6); w++) woff += wsum[w];
        int excl = woff + inc - v;
        lcur[tid] = excl;
        int node = lo + tid;
        if (node < N_NODES) rowstart[node] = base + excl;
    }
    if (b == 0 && tid == 0) rowstart[N_NODES] = N_EDGES;
    __syncthreads();
    for (int i = tid; i < myCount; i += 1024) {
        unsigned p = my[i];
        int pos = atomicAdd(&lcur[p >> 16], 1);
        esrc[base + pos] = (int)(p & 0xFFFFu);
    }
}

// ---------------- W pre-pack into MFMA B-fragment layout + workspace zeroing ----------------
__global__ void k_wpack(const float* __restrict__ W0, const float* __restrict__ W1,
                        const float* __restrict__ W2, __half* __restrict__ wpk,
                        float* __restrict__ bn_part, int* __restrict__ g_cursor) {
    int gid = blockIdx.x * 256 + threadIdx.x;  // 24 * 256 = 6144
    {
        int z0 = gid * 8;
        if (z0 < 3 * BN_BUCKETS * 256) {
            float4 z = make_float4(0.f, 0.f, 0.f, 0.f);
            *reinterpret_cast<float4*>(&bn_part[z0]) = z;
            *reinterpret_cast<float4*>(&bn_part[z0 + 4]) = z;
        }
        if (gid < NB2) g_cursor[gid] = 0;
    }
    if (gid >= 3 * 2048) return;
    int L = gid >> 11;
    int rem = gid & 2047;
    int ct = rem >> 8;
    int kc = (rem >> 6) & 3;
    int l = rem & 63;
    const float* W = (L == 0) ? W0 : ((L == 1) ? W1 : W2);
    int c = ct * 16 + (l & 15);
    int k0 = kc * 32 + (l >> 4) * 8;
    __half tmp[8];
#pragma unroll
    for (int j = 0; j < 8; j++) tmp[j] = __float2half(W[(k0 + j) * HDIM + c]);
    *reinterpret_cast<float4*>(&wpk[((size_t)L << 14) + ((size_t)(ct * 4 + kc) * 64 + l) * 8]) =
        *reinterpret_cast<float4*>(tmp);
}

// ---------------- GEMM v6: MFMA 16x16x32_f16, BN finalize fused in prologue ----------------
__global__ void k_gemm6(const __half* __restrict__ h, const int* __restrict__ xidx,
                        const float* __restrict__ embed, const f16x8* __restrict__ wB,
                        __half* __restrict__ feat_h, const float* __restrict__ bn_prev,
                        const float* __restrict__ gamma, const float* __restrict__ beta,
                        const float* __restrict__ al, const float* __restrict__ ar,
                        float* __restrict__ el, float* __restrict__ er, int mode) {
    __shared__ __half sf[4][16][136];  // per-wave 16x128 fp16 tile (+8 pad), 17.4 KB
    __shared__ __align__(16) float s_sc[128];
    __shared__ __align__(16) float s_sh[128];
    int tid = threadIdx.x;
    // ---- BN finalize prologue (redundant per block; bn_prev is L2-resident 16 KB) ----
    if (mode != 0) {
        float* red = reinterpret_cast<float*>(sf);   // alias; sf written after
        int c = tid & 127, which = tid >> 7;
        float t = 0.f;
#pragma unroll
        for (int b = 0; b < BN_BUCKETS; b++) t += bn_prev[b * 256 + which * 128 + c];
        red[tid] = t;
        __syncthreads();
        if (tid < 128) {
            float mu = red[tid] * (1.f / N_NODES);
            float var = red[128 + tid] * (1.f / N_NODES) - mu * mu;
            float sc = gamma[tid] * rsqrtf(var + 1e-5f);
            s_sc[tid] = sc;
            s_sh[tid] = beta[tid] - mu * sc;
        }
        __syncthreads();
    }
    int w = tid >> 6, lane = tid & 63;
    int r = lane & 15, kg = lane >> 4;
    int wbase = blockIdx.x * 64 + w * 16;
    int n = wbase + r;
    bool ok = n < N_NODES;

    // ---- A fragments: aF[kc][j] = act[n][kc*32 + kg*8 + j] ----
    f16x8 aF[4];
#pragma unroll
    for (int kc = 0; kc < 4; kc++)
#pragma unroll
        for (int j = 0; j < 8; j++) aF[kc][j] = (_Float16)0.f;
    if (ok) {
        if (mode == 0) {
            int xi = xidx[n];
            const float* ep = embed + (size_t)xi * HDIM;
#pragma unroll
            for (int kc = 0; kc < 4; kc++) {
                int c0 = kc * 32 + kg * 8;
                float4 e0 = *reinterpret_cast<const float4*>(ep + c0);
                float4 e1 = *reinterpret_cast<const float4*>(ep + c0 + 4);
                aF[kc][0] = (_Float16)e0.x; aF[kc][1] = (_Float16)e0.y;
                aF[kc][2] = (_Float16)e0.z; aF[kc][3] = (_Float16)e0.w;
                aF[kc][4] = (_Float16)e1.x; aF[kc][5] = (_Float16)e1.y;
                aF[kc][6] = (_Float16)e1.z; aF[kc][7] = (_Float16)e1.w;
            }
        } else {
            const __half* hp = h + (size_t)n * HDIM;
#pragma unroll
            for (int kc = 0; kc < 4; kc++) {
                int c0 = kc * 32 + kg * 8;
                float4 raw = *reinterpret_cast<const float4*>(hp + c0);
                const __half2* u = reinterpret_cast<const __half2*>(&raw);
                float4 sc0 = *reinterpret_cast<const float4*>(&s_sc[c0]);
                float4 sc1 = *reinterpret_cast<const float4*>(&s_sc[c0 + 4]);
                float4 sh0 = *reinterpret_cast<const float4*>(&s_sh[c0]);
                float4 sh1 = *reinterpret_cast<const float4*>(&s_sh[c0 + 4]);
                float scv[8] = {sc0.x, sc0.y, sc0.z, sc0.w, sc1.x, sc1.y, sc1.z, sc1.w};
                float shv[8] = {sh0.x, sh0.y, sh0.z, sh0.w, sh1.x, sh1.y, sh1.z, sh1.w};
                float vv[8];
#pragma unroll
                for (int t = 0; t < 4; t++) {
                    vv[2 * t] = __half2float(__low2half(u[t]));
                    vv[2 * t + 1] = __half2float(__high2half(u[t]));
                }
#pragma unroll
                for (int j = 0; j < 8; j++) {
                    float t = vv[j] * scv[j] + shv[j];
                    aF[kc][j] = (_Float16)elu1(t);
                }
            }
        }
    }
    if (mode != 0) __syncthreads();  // red alias done before sf writes

    // ---- MFMA main: acc[ct] over 4 K-chunks ----
    f32x4 acc[8] = {};
#pragma unroll
    for (int kc = 0; kc < 4; kc++) {
#pragma unroll
        for (int ct = 0; ct < 8; ct++) {
            f16x8 bF = wB[(ct * 4 + kc) * 64 + lane];
            acc[ct] = __builtin_amdgcn_mfma_f32_16x16x32_f16(aF[kc], bF, acc[ct], 0, 0, 0);
        }
    }

    // ---- feat store: C/D layout col=lane&15 (within ct), row=kg*4+reg ----
#pragma unroll
    for (int ct = 0; ct < 8; ct++)
#pragma unroll
        for (int reg = 0; reg < 4; reg++)
            sf[w][kg * 4 + reg][ct * 16 + r] = __float2half(acc[ct][reg]);
    __syncthreads();
#pragma unroll
    for (int q = 0; q < 4; q++) {
        int row = q * 4 + kg;
        int n2 = wbase + row;
        if (n2 < N_NODES) {
            float4 v = *reinterpret_cast<const float4*>(&sf[w][row][r * 8]);
            *reinterpret_cast<float4*>(&feat_h[(size_t)n2 * HDIM + r * 8]) = v;
        }
    }

    // ---- fused el/er: head hd covers ct=2hd, 2hd+1; reduce over 16 lanes (cols) ----
    float alq[8], arq[8];
#pragma unroll
    for (int ct = 0; ct < 8; ct++) {
        alq[ct] = al[ct * 16 + r];
        arq[ct] = ar[ct * 16 + r];
    }
#pragma unroll
    for (int hd = 0; hd < 4; hd++) {
        float pl[4], pr[4];
#pragma unroll
        for (int reg = 0; reg < 4; reg++) {
            pl[reg] = acc[2 * hd][reg] * alq[2 * hd] + acc[2 * hd + 1][reg] * alq[2 * hd + 1];
            pr[reg] = acc[2 * hd][reg] * arq[2 * hd] + acc[2 * hd + 1][reg] * arq[2 * hd + 1];
        }
#pragma unroll
        for (int off = 1; off < 16; off <<= 1)
#pragma unroll
            for (int reg = 0; reg < 4; reg++) {
                pl[reg] += __shfl_xor(pl[reg], off, 64);
                pr[reg] += __shfl_xor(pr[reg], off, 64);
            }
        if (r == 0) {
#pragma unroll
            for (int reg = 0; reg < 4; reg++) {
                int n2 = wbase + kg * 4 + reg;
                if (n2 < N_NODES) {
                    el[n2 * 4 + hd] = pl[reg];
                    er[n2 * 4 + hd] = pr[reg];
                }
            }
        }
    }
}

// ---------------- aggregation v11: fma_mix hot loop + 32-bit addressing ----------------
__global__ void k_agg11(const __half* __restrict__ feat_h, const float* __restrict__ el,
                        const float* __restrict__ er, const int* __restrict__ rowstart,
                        const int* __restrict__ esrc, const float* __restrict__ snorm_n,
                        __half* __restrict__ h, const float* __restrict__ bn_prev,
                        const float* __restrict__ gamma, const float* __restrict__ beta,
                        float* __restrict__ bn_cur, int layer) {
    __shared__ __align__(16) int2 lds[4][2][2][32][4];  // [wave][h2][buf][slot][head], 16 KB
    __shared__ __align__(16) float s_sc[128];
    __shared__ __align__(16) float s_sh[128];
    int tid = threadIdx.x;
    // ---- BN finalize prologue for residual path (layer > 0) ----
    if (layer > 0) {
        float* red = reinterpret_cast<float*>(lds);  // alias; lds rewritten after barrier
        int c = tid & 127, which = tid >> 7;
        float t = 0.f;
#pragma unroll
        for (int b = 0; b < BN_BUCKETS; b++) t += bn_prev[b * 256 + which * 128 + c];
        red[tid] = t;
        __syncthreads();
        if (tid < 128) {
            float mu = red[tid] * (1.f / N_NODES);
            float var = red[128 + tid] * (1.f / N_NODES) - mu * mu;
            float sc = gamma[tid] * rsqrtf(var + 1e-5f);
            s_sc[tid] = sc;
            s_sh[tid] = beta[tid] - mu * sc;
        }
        __syncthreads();
    }
    int wave = tid >> 6, lane = tid & 63;
    int h2 = lane >> 5, hl = lane & 31;
    int dp = hl & 15, epair = hl >> 4, head = dp >> 2;
    unsigned dpo = (unsigned)dp << 4;               // byte offset within feat row
    const char* fb = reinterpret_cast<const char*>(feat_h);
    const char* eb = reinterpret_cast<const char*>(el);
    int n = blockIdx.x * 8 + wave * 2 + h2;   // 6250 blocks * 8 = 50000 exactly
    int e0 = rowstart[n];
    int deg = rowstart[n + 1] - e0;           // >= 1 (self loops)
    int dmax = max(deg, __shfl_xor(deg, 32, 64));
    float4 er4 = *(const float4*)&er[n * 4];
    float s = 0.f;
    float a[8] = {};
    int nch = (dmax + 31) >> 5;

    int idx0 = e0 + min(hl, deg - 1);
    int sidx_p = esrc[idx0];
    float4 el_p = *reinterpret_cast<const float4*>(eb + ((unsigned)sidx_p << 4));
    bool val_p = hl < deg;

    for (int c = 0; c < nch; c++) {
        float w0 = 0.f, w1 = 0.f, w2 = 0.f, w3 = 0.f;
        int sv = sidx_p;
        if (val_p) {
            float ex = el_p.x + er4.x, ey = el_p.y + er4.y;
            float ez = el_p.z + er4.z, ew = el_p.w + er4.w;
            ex = fmaxf(ex, 0.f) + 0.2f * fminf(ex, 0.f);
            ey = fmaxf(ey, 0.f) + 0.2f * fminf(ey, 0.f);
            ez = fmaxf(ez, 0.f) + 0.2f * fminf(ez, 0.f);
            ew = fmaxf(ew, 0.f) + 0.2f * fminf(ew, 0.f);
            w0 = __expf(ex); w1 = __expf(ey); w2 = __expf(ez); w3 = __expf(ew);
        }
        int4* wp = reinterpret_cast<int4*>(&lds[wave][h2][c & 1][hl][0]);
        wp[0] = make_int4(sv, __float_as_int(w0), sv, __float_as_int(w1));
        wp[1] = make_int4(sv, __float_as_int(w2), sv, __float_as_int(w3));
        if (c + 1 < nch) {
            int slot = (c + 1) * 32 + hl;
            int idx = e0 + min(slot, deg - 1);
            sidx_p = esrc[idx];
            el_p = *reinterpret_cast<const float4*>(eb + ((unsigned)sidx_p << 4));
            val_p = slot < deg;
        }
        int cnt = min(32, dmax - c * 32);
        int iters = (cnt + 1) >> 1;
#pragma unroll 2
        for (int j = 0; j < iters; j++) {
            int2 rec = lds[wave][h2][c & 1][j * 2 + epair][head];
            float w = __int_as_float(rec.y);
            unsigned boff = ((unsigned)rec.x << 8) + dpo;
            uint4 u = *reinterpret_cast<const uint4*>(fb + boff);
            FMAMIX_LO(a[0], u.x, w); FMAMIX_HI(a[1], u.x, w);
            FMAMIX_LO(a[2], u.y, w); FMAMIX_HI(a[3], u.y, w);
            FMAMIX_LO(a[4], u.z, w); FMAMIX_HI(a[5], u.z, w);
            FMAMIX_LO(a[6], u.w, w); FMAMIX_HI(a[7], u.w, w);
            s += w;
        }
    }
#pragma unroll
    for (int k = 0; k < 8; k++) a[k] += __shfl_xor(a[k], 16, 64);
    s += __shfl_xor(s, 16, 64);
    float r[8] = {};
    if (epair == 0) {
        float inv = 1.f / s;
        int d0 = dp * 8;
#pragma unroll
        for (int k = 0; k < 8; k++) r[k] = a[k] * inv;
        if (layer > 0) {
            float4 hraw = *reinterpret_cast<const float4*>(&h[(size_t)n * HDIM + d0]);
            __half2 q0 = *(__half2*)&hraw.x, q1 = *(__half2*)&hraw.y;
            __half2 q2 = *(__half2*)&hraw.z, q3 = *(__half2*)&hraw.w;
            float hv[8] = {__half2float(__low2half(q0)), __half2float(__high2half(q0)),
                           __half2float(__low2half(q1)), __half2float(__high2half(q1)),
                           __half2float(__low2half(q2)), __half2float(__high2half(q2)),
                           __half2float(__low2half(q3)), __half2float(__high2half(q3))};
            float4 sc0 = *reinterpret_cast<const float4*>(&s_sc[d0]);
            float4 sc1 = *reinterpret_cast<const float4*>(&s_sc[d0 + 4]);
            float4 sh0 = *reinterpret_cast<const float4*>(&s_sh[d0]);
            float4 sh1 = *reinterpret_cast<const float4*>(&s_sh[d0 + 4]);
            float scv[8] = {sc0.x, sc0.y, sc0.z, sc0.w, sc1.x, sc1.y, sc1.z, sc1.w};
            float shv[8] = {sh0.x, sh0.y, sh0.z, sh0.w, sh1.x, sh1.y, sh1.z, sh1.w};
#pragma unroll
            for (int k = 0; k < 8; k++) {
                float t = hv[k] * scv[k] + shv[k];
                r[k] += elu1(t);
                r[k] = elu1(r[k]);
            }
        }
        float sn = snorm_n[n];
#pragma unroll
        for (int k = 0; k < 8; k++) r[k] *= sn;
        float4 outv;
        *(__half2*)&outv.x = __floats2half2_rn(r[0], r[1]);
        *(__half2*)&outv.y = __floats2half2_rn(r[2], r[3]);
        *(__half2*)&outv.z = __floats2half2_rn(r[4], r[5]);
        *(__half2*)&outv.w = __floats2half2_rn(r[6], r[7]);
        *reinterpret_cast<float4*>(&h[(size_t)n * HDIM + d0]) = outv;
    }

    // ---- BN partials: per-block LDS reduce + one atomicAdd per (c,which); NO fences ----
    float* bsum = reinterpret_cast<float*>(lds);   // 2048 floats used (of 4096)
    __syncthreads();          // all waves done with their lds hot-loop regions
    if (epair == 0) {
        int n8 = wave * 2 + h2;
        int cbase = n8 * 128 + dp * 8;
#pragma unroll
        for (int k = 0; k < 8; k++) {
            bsum[cbase + k] = r[k];
            bsum[1024 + cbase + k] = r[k] * r[k];
        }
    }
    __syncthreads();
    {
        int c = tid & 127, which = tid >> 7;   // which: 0=sum, 1=sumsq
        float v = 0.f;
#pragma unroll
        for (int n8 = 0; n8 < 8; n8++) v += bsum[which * 1024 + n8 * 128 + c];
        atomicAdd(&bn_cur[(blockIdx.x & (BN_BUCKETS - 1)) * 256 + which * 128 + c], v);
    }
}

// ---------------- classifier (h fp16), BN finalize fused ----------------
__global__ void k_classifier(const __half* __restrict__ h, const float* __restrict__ W1,
                             const float* __restrict__ b1, const float* __restrict__ W2,
                             const float* __restrict__ b2, const float* __restrict__ bn_prev,
                             const float* __restrict__ gamma, const float* __restrict__ beta,
                             float* __restrict__ out) {
    __shared__ float hs[16][128];
    __shared__ __align__(16) float s_sc[128];
    __shared__ __align__(16) float s_sh[128];
    int tid = threadIdx.x;
    {
        float* red = &hs[0][0];   // alias; hs written after
        int c = tid & 127, which = tid >> 7;
        float t = 0.f;
#pragma unroll
        for (int b = 0; b < BN_BUCKETS; b++) t += bn_prev[b * 256 + which * 128 + c];
        red[tid] = t;
        __syncthreads();
        if (tid < 128) {
            float mu = red[tid] * (1.f / N_NODES);
            float var = red[128 + tid] * (1.f / N_NODES) - mu * mu;
            float sc = gamma[tid] * rsqrtf(var + 1e-5f);
            s_sc[tid] = sc;
            s_sh[tid] = beta[tid] - mu * sc;
        }
        __syncthreads();
    }
    int nbase = blockIdx.x * 16;
    for (int i = tid; i < 16 * 128; i += 256) {
        int r = i >> 7, c = i & 127;
        int n = nbase + r;
        float v = 0.f;
        if (n < N_NODES) {
            v = __half2float(h[(size_t)n * HDIM + c]) * s_sc[c] + s_sh[c];
            v = elu1(v);
        }
        hs[r][c] = v;
    }
    __syncthreads();
    int j = tid & 63;
    int g = tid >> 6;
    float bj = b1[j];
    float acc[4] = {bj, bj, bj, bj};
    for (int k = 0; k < 128; k++) {
        float w = W1[k * 64 + j];
#pragma unroll
        for (int i = 0; i < 4; i++) acc[i] += hs[g * 4 + i][k] * w;
    }
    float w20 = W2[j * 2], w21 = W2[j * 2 + 1];
    float res[8];
#pragma unroll
    for (int i = 0; i < 4; i++) {
        float hid = fmaxf(acc[i], 0.f);
        res[2 * i] = hid * w20;
        res[2 * i + 1] = hid * w21;
    }
#pragma unroll
    for (int off = 1; off < 64; off <<= 1)
#pragma unroll
        for (int i = 0; i < 8; i++) res[i] += __shfl_xor(res[i], off, 64);
    if (j < 8) {
        int n = nbase + g * 4 + (j >> 1);
        if (n < N_NODES) out[n * 2 + (j & 1)] = res[j] + b2[j & 1];
    }
}

// ----------------------------------------------------------------
extern "C" void kernel_launch(void* const* d_in, const int* in_sizes, int n_in,
                              void* d_out, int out_size, void* d_ws, size_t ws_size,
                              hipStream_t stream) {
    const int* x = (const int*)d_in[0];
    const int* src = (const int*)d_in[1];
    const int* dst = (const int*)d_in[2];
    const float* snorm_n = (const float*)d_in[3];
    const float* embed = (const float*)d_in[5];
    const float* Ws[3] = {(const float*)d_in[6], (const float*)d_in[11], (const float*)d_in[16]};
    const float* als[3] = {(const float*)d_in[7], (const float*)d_in[12], (const float*)d_in[17]};
    const float* ars[3] = {(const float*)d_in[8], (const float*)d_in[13], (const float*)d_in[18]};
    const float* gms[3] = {(const float*)d_in[9], (const float*)d_in[14], (const float*)d_in[19]};
    const float* bts[3] = {(const float*)d_in[10], (const float*)d_in[15], (const float*)d_in[20]};
    const float* cls1_w = (const float*)d_in[21];
    const float* cls1_b = (const float*)d_in[22];
    const float* cls2_w = (const float*)d_in[23];
    const float* cls2_b = (const float*)d_in[24];
    float* out = (float*)d_out;

    char* ws = (char*)d_ws;
    size_t off = 0;
    auto alloc = [&](size_t bytes) {
        void* p = ws + off;
        off = (off + bytes + 255) & ~(size_t)255;
        return p;
    };
    __half* h = (__half*)alloc((size_t)N_NODES * HDIM * 2);
    __half* feat_h = (__half*)alloc((size_t)N_NODES * HDIM * 2);
    float* el = (float*)alloc((size_t)N_NODES * 4 * 4);
    float* er = (float*)alloc((size_t)N_NODES * 4 * 4);
    int* rowstart = (int*)alloc((size_t)(N_NODES + 1) * 4);
    int* esrc = (int*)alloc((size_t)N_EDGES * 4);
    int* g_cursor = (int*)alloc((size_t)NB2 * 4);
    float* bn_part = (float*)alloc((size_t)3 * BN_BUCKETS * 256 * 4);
    __half* wpkh = (__half*)alloc((size_t)3 * 16384 * 2);
    unsigned* g_bucket = (unsigned*)feat_h;  // 4 MB alias; CSR build finishes before gemm
    (void)ws_size; (void)in_sizes; (void)n_in; (void)out_size;

    k_wpack<<<(3 * 2048 + 255) / 256, 256, 0, stream>>>(Ws[0], Ws[1], Ws[2], wpkh,
                                                        bn_part, g_cursor);
    k_partA<<<GA, 1024, 0, stream>>>(src, dst, g_cursor, g_bucket);
    k_partB<<<NB2, 1024, 0, stream>>>(g_bucket, g_cursor, rowstart, esrc);

    for (int L = 0; L < 3; L++) {
        const f16x8* wB = reinterpret_cast<const f16x8*>(wpkh + ((size_t)L << 14));
        const float* bn_prev = bn_part + (size_t)(L == 0 ? 0 : L - 1) * BN_BUCKETS * 256;
        float* bn_cur = bn_part + (size_t)L * BN_BUCKETS * 256;
        int gprev = (L == 0) ? 0 : L - 1;
        k_gemm6<<<(N_NODES + 63) / 64, 256, 0, stream>>>(h, x, embed, wB, feat_h,
                                                         bn_prev, gms[gprev], bts[gprev],
                                                         als[L], ars[L], el, er, L == 0 ? 0 : 1);
        k_agg11<<<AGG_BLOCKS, 256, 0, stream>>>(feat_h, el, er, rowstart, esrc,
                                                snorm_n, h, bn_prev, gms[gprev], bts[gprev],
                                                bn_cur, L);
    }

    k_classifier<<<(N_NODES + 15) / 16, 256, 0, stream>>>(h, cls1_w, cls1_b, cls2_w, cls2_b,
                                                          bn_part + (size_t)2 * BN_BUCKETS * 256,
                                                          gms[2], bts[2], out);
}

// Round 6
// 330.877 us; speedup vs baseline: 1.0440x; 1.0440x over previous
//
#include <hip/hip_runtime.h>
#include <hip/hip_bf16.h>
#include <hip/hip_fp16.h>
#include <math.h>

constexpr int N_NODES = 50000;
constexpr int N_EDGES = 850000;
constexpr int HDIM = 128;   // H*D
constexpr int AGG_BLOCKS = N_NODES / 8;  // 6250
constexpr int BN_BUCKETS = 16;

typedef _Float16 f16x8 __attribute__((ext_vector_type(8)));
typedef float f32x4 __attribute__((ext_vector_type(4)));

// v_fma_mix_f32: acc += f16(lo/hi of pk) * w   (exact f16->f32 convert inside FMA)
#define FMAMIX_LO(acc, pk, w) \
    asm("v_fma_mix_f32 %0, %1, %2, %0 op_sel:[0,0,0] op_sel_hi:[1,0,0]" \
        : "+v"(acc) : "v"(pk), "v"(w))
#define FMAMIX_HI(acc, pk, w) \
    asm("v_fma_mix_f32 %0, %1, %2, %0 op_sel:[1,0,0] op_sel_hi:[1,0,0]" \
        : "+v"(acc) : "v"(pk), "v"(w))

__device__ __forceinline__ float elu1(float t) {
    return (t > 0.f) ? t : (__expf(t) - 1.f);
}

// ---------------- CSR build: two-phase bucket sort ----------------
constexpr int NB2 = 128;                                // buckets
constexpr int RANGE2 = (N_NODES + NB2 - 1) / NB2;       // 391 nodes/bucket
constexpr int CAP = 8192;                               // bucket capacity (avg 6641)
constexpr int CHUNK = 8192;                             // edges per phase-A block
constexpr int GA = (N_EDGES + CHUNK - 1) / CHUNK;       // 104 blocks

__global__ void k_partA(const int* __restrict__ src, const int* __restrict__ dst,
                        int* __restrict__ g_cursor, unsigned* __restrict__ bucket) {
    __shared__ int hist[NB2];
    int tid = threadIdx.x;
    int e0 = blockIdx.x * CHUNK;
    int e1 = min(e0 + CHUNK, N_EDGES);
    if (tid < NB2) hist[tid] = 0;
    __syncthreads();
    for (int i = e0 + tid; i < e1; i += 1024) {
        int d = dst[i];
        atomicAdd(&hist[d / RANGE2], 1);
    }
    __syncthreads();
    int base = 0;
    if (tid < NB2) base = atomicAdd(&g_cursor[tid], hist[tid]);
    __syncthreads();
    if (tid < NB2) hist[tid] = base;
    __syncthreads();
    for (int i = e0 + tid; i < e1; i += 1024) {
        int d = dst[i];
        int s = src[i];
        int b = d / RANGE2;
        int p = atomicAdd(&hist[b], 1);
        bucket[b * CAP + p] = (unsigned)s | ((unsigned)(d - b * RANGE2) << 16);
    }
}

__global__ void k_partB(const unsigned* __restrict__ bucket, const int* __restrict__ cnts,
                        int* __restrict__ rowstart, int* __restrict__ esrc) {
    __shared__ int cnt_s[NB2];
    __shared__ int hist[RANGE2];
    __shared__ int lcur[RANGE2];
    __shared__ int wsum[7];
    int b = blockIdx.x, tid = threadIdx.x;
    int lo = b * RANGE2;
    int myCount = cnts[b];
    if (tid < NB2) cnt_s[tid] = cnts[tid];
    __syncthreads();
    for (int off = 1; off < NB2; off <<= 1) {
        int t = (tid < NB2 && tid >= off) ? cnt_s[tid - off] : 0;
        __syncthreads();
        if (tid < NB2) cnt_s[tid] += t;
        __syncthreads();
    }
    int base = cnt_s[b] - myCount;
    for (int j = tid; j < RANGE2; j += 1024) hist[j] = 0;
    __syncthreads();
    const unsigned* my = bucket + (size_t)b * CAP;
    for (int i = tid; i < myCount; i += 1024) atomicAdd(&hist[my[i] >> 16], 1);
    __syncthreads();
    int v = 0;
    if (tid < 448) v = (tid < RANGE2) ? hist[tid] : 0;
    int inc = v;
    int lane = tid & 63;
#pragma unroll
    for (int off = 1; off < 64; off <<= 1) {
        int t = __shfl_up(inc, off, 64);
        if (lane >= off) inc += t;
    }
    if (tid < 448 && lane == 63) wsum[tid >> 6] = inc;
    __syncthreads();
    if (tid < RANGE2) {
        int woff = 0;
        for (int w = 0; w < (tid >> 6); w++) woff += wsum[w];
        int excl = woff + inc - v;
        lcur[tid] = excl;
        int node = lo + tid;
        if (node < N_NODES) rowstart[node] = base + excl;
    }
    if (b == 0 && tid == 0) rowstart[N_NODES] = N_EDGES;
    __syncthreads();
    for (int i = tid; i < myCount; i += 1024) {
        unsigned p = my[i];
        int pos = atomicAdd(&lcur[p >> 16], 1);
        esrc[base + pos] = (int)(p & 0xFFFFu);
    }
}

// ---------------- W pre-pack into MFMA B-fragment layout + workspace zeroing ----------------
__global__ void k_wpack(const float* __restrict__ W0, const float* __restrict__ W1,
                        const float* __restrict__ W2, __half* __restrict__ wpk,
                        float* __restrict__ bn_part, int* __restrict__ g_cursor) {
    int gid = blockIdx.x * 256 + threadIdx.x;  // 24 * 256 = 6144
    {
        int z0 = gid * 8;
        if (z0 < 3 * BN_BUCKETS * 256) {
            float4 z = make_float4(0.f, 0.f, 0.f, 0.f);
            *reinterpret_cast<float4*>(&bn_part[z0]) = z;
            *reinterpret_cast<float4*>(&bn_part[z0 + 4]) = z;
        }
        if (gid < NB2) g_cursor[gid] = 0;
    }
    if (gid >= 3 * 2048) return;
    int L = gid >> 11;
    int rem = gid & 2047;
    int ct = rem >> 8;
    int kc = (rem >> 6) & 3;
    int l = rem & 63;
    const float* W = (L == 0) ? W0 : ((L == 1) ? W1 : W2);
    int c = ct * 16 + (l & 15);
    int k0 = kc * 32 + (l >> 4) * 8;
    __half tmp[8];
#pragma unroll
    for (int j = 0; j < 8; j++) tmp[j] = __float2half(W[(k0 + j) * HDIM + c]);
    *reinterpret_cast<float4*>(&wpk[((size_t)L << 14) + ((size_t)(ct * 4 + kc) * 64 + l) * 8]) =
        *reinterpret_cast<float4*>(tmp);
}

// ---------------- GEMM v6: MFMA 16x16x32_f16, BN finalize fused in prologue ----------------
__global__ void k_gemm6(const __half* __restrict__ h, const int* __restrict__ xidx,
                        const float* __restrict__ embed, const f16x8* __restrict__ wB,
                        __half* __restrict__ feat_h, const float* __restrict__ bn_prev,
                        const float* __restrict__ gamma, const float* __restrict__ beta,
                        const float* __restrict__ al, const float* __restrict__ ar,
                        float* __restrict__ el, float* __restrict__ er, int mode) {
    __shared__ __half sf[4][16][136];  // per-wave 16x128 fp16 tile (+8 pad), 17.4 KB
    __shared__ __align__(16) float s_sc[128];
    __shared__ __align__(16) float s_sh[128];
    int tid = threadIdx.x;
    // ---- BN finalize prologue (redundant per block; bn_prev is L2-resident 16 KB) ----
    if (mode != 0) {
        float* red = reinterpret_cast<float*>(sf);   // alias; sf written after
        int c = tid & 127, which = tid >> 7;
        float t = 0.f;
#pragma unroll
        for (int b = 0; b < BN_BUCKETS; b++) t += bn_prev[b * 256 + which * 128 + c];
        red[tid] = t;
        __syncthreads();
        if (tid < 128) {
            float mu = red[tid] * (1.f / N_NODES);
            float var = red[128 + tid] * (1.f / N_NODES) - mu * mu;
            float sc = gamma[tid] * rsqrtf(var + 1e-5f);
            s_sc[tid] = sc;
            s_sh[tid] = beta[tid] - mu * sc;
        }
        __syncthreads();
    }
    int w = tid >> 6, lane = tid & 63;
    int r = lane & 15, kg = lane >> 4;
    int wbase = blockIdx.x * 64 + w * 16;
    int n = wbase + r;
    bool ok = n < N_NODES;

    // ---- A fragments: aF[kc][j] = act[n][kc*32 + kg*8 + j] ----
    f16x8 aF[4];
#pragma unroll
    for (int kc = 0; kc < 4; kc++)
#pragma unroll
        for (int j = 0; j < 8; j++) aF[kc][j] = (_Float16)0.f;
    if (ok) {
        if (mode == 0) {
            int xi = xidx[n];
            const float* ep = embed + (size_t)xi * HDIM;
#pragma unroll
            for (int kc = 0; kc < 4; kc++) {
                int c0 = kc * 32 + kg * 8;
                float4 e0 = *reinterpret_cast<const float4*>(ep + c0);
                float4 e1 = *reinterpret_cast<const float4*>(ep + c0 + 4);
                aF[kc][0] = (_Float16)e0.x; aF[kc][1] = (_Float16)e0.y;
                aF[kc][2] = (_Float16)e0.z; aF[kc][3] = (_Float16)e0.w;
                aF[kc][4] = (_Float16)e1.x; aF[kc][5] = (_Float16)e1.y;
                aF[kc][6] = (_Float16)e1.z; aF[kc][7] = (_Float16)e1.w;
            }
        } else {
            const __half* hp = h + (size_t)n * HDIM;
#pragma unroll
            for (int kc = 0; kc < 4; kc++) {
                int c0 = kc * 32 + kg * 8;
                float4 raw = *reinterpret_cast<const float4*>(hp + c0);
                const __half2* u = reinterpret_cast<const __half2*>(&raw);
                float4 sc0 = *reinterpret_cast<const float4*>(&s_sc[c0]);
                float4 sc1 = *reinterpret_cast<const float4*>(&s_sc[c0 + 4]);
                float4 sh0 = *reinterpret_cast<const float4*>(&s_sh[c0]);
                float4 sh1 = *reinterpret_cast<const float4*>(&s_sh[c0 + 4]);
                float scv[8] = {sc0.x, sc0.y, sc0.z, sc0.w, sc1.x, sc1.y, sc1.z, sc1.w};
                float shv[8] = {sh0.x, sh0.y, sh0.z, sh0.w, sh1.x, sh1.y, sh1.z, sh1.w};
                float vv[8];
#pragma unroll
                for (int t = 0; t < 4; t++) {
                    vv[2 * t] = __half2float(__low2half(u[t]));
                    vv[2 * t + 1] = __half2float(__high2half(u[t]));
                }
#pragma unroll
                for (int j = 0; j < 8; j++) {
                    float t = vv[j] * scv[j] + shv[j];
                    aF[kc][j] = (_Float16)elu1(t);
                }
            }
        }
    }
    if (mode != 0) __syncthreads();  // red alias done before sf writes

    // ---- MFMA main: acc[ct] over 4 K-chunks ----
    f32x4 acc[8] = {};
#pragma unroll
    for (int kc = 0; kc < 4; kc++) {
#pragma unroll
        for (int ct = 0; ct < 8; ct++) {
            f16x8 bF = wB[(ct * 4 + kc) * 64 + lane];
            acc[ct] = __builtin_amdgcn_mfma_f32_16x16x32_f16(aF[kc], bF, acc[ct], 0, 0, 0);
        }
    }

    // ---- feat store: C/D layout col=lane&15 (within ct), row=kg*4+reg ----
#pragma unroll
    for (int ct = 0; ct < 8; ct++)
#pragma unroll
        for (int reg = 0; reg < 4; reg++)
            sf[w][kg * 4 + reg][ct * 16 + r] = __float2half(acc[ct][reg]);
    __syncthreads();
#pragma unroll
    for (int q = 0; q < 4; q++) {
        int row = q * 4 + kg;
        int n2 = wbase + row;
        if (n2 < N_NODES) {
            float4 v = *reinterpret_cast<const float4*>(&sf[w][row][r * 8]);
            *reinterpret_cast<float4*>(&feat_h[(size_t)n2 * HDIM + r * 8]) = v;
        }
    }

    // ---- fused el/er: head hd covers ct=2hd, 2hd+1; reduce over 16 lanes (cols) ----
    float alq[8], arq[8];
#pragma unroll
    for (int ct = 0; ct < 8; ct++) {
        alq[ct] = al[ct * 16 + r];
        arq[ct] = ar[ct * 16 + r];
    }
#pragma unroll
    for (int hd = 0; hd < 4; hd++) {
        float pl[4], pr[4];
#pragma unroll
        for (int reg = 0; reg < 4; reg++) {
            pl[reg] = acc[2 * hd][reg] * alq[2 * hd] + acc[2 * hd + 1][reg] * alq[2 * hd + 1];
            pr[reg] = acc[2 * hd][reg] * arq[2 * hd] + acc[2 * hd + 1][reg] * arq[2 * hd + 1];
        }
#pragma unroll
        for (int off = 1; off < 16; off <<= 1)
#pragma unroll
            for (int reg = 0; reg < 4; reg++) {
                pl[reg] += __shfl_xor(pl[reg], off, 64);
                pr[reg] += __shfl_xor(pr[reg], off, 64);
            }
        if (r == 0) {
#pragma unroll
            for (int reg = 0; reg < 4; reg++) {
                int n2 = wbase + kg * 4 + reg;
                if (n2 < N_NODES) {
                    el[n2 * 4 + hd] = pl[reg];
                    er[n2 * 4 + hd] = pr[reg];
                }
            }
        }
    }
}

// ---------------- aggregation v12: 4-deep gather pipeline (MLP), fma_mix consume ----------------
__global__ void k_agg12(const __half* __restrict__ feat_h, const float* __restrict__ el,
                        const float* __restrict__ er, const int* __restrict__ rowstart,
                        const int* __restrict__ esrc, const float* __restrict__ snorm_n,
                        __half* __restrict__ h, const float* __restrict__ bn_prev,
                        const float* __restrict__ gamma, const float* __restrict__ beta,
                        float* __restrict__ bn_cur, int layer) {
    __shared__ __align__(16) int2 lds[4][2][2][32][4];  // [wave][h2][buf][slot][head], 16 KB
    __shared__ __align__(16) float s_sc[128];
    __shared__ __align__(16) float s_sh[128];
    int tid = threadIdx.x;
    // ---- BN finalize prologue for residual path (layer > 0) ----
    if (layer > 0) {
        float* red = reinterpret_cast<float*>(lds);  // alias; lds rewritten after barrier
        int c = tid & 127, which = tid >> 7;
        float t = 0.f;
#pragma unroll
        for (int b = 0; b < BN_BUCKETS; b++) t += bn_prev[b * 256 + which * 128 + c];
        red[tid] = t;
        __syncthreads();
        if (tid < 128) {
            float mu = red[tid] * (1.f / N_NODES);
            float var = red[128 + tid] * (1.f / N_NODES) - mu * mu;
            float sc = gamma[tid] * rsqrtf(var + 1e-5f);
            s_sc[tid] = sc;
            s_sh[tid] = beta[tid] - mu * sc;
        }
        __syncthreads();
    }
    int wave = tid >> 6, lane = tid & 63;
    int h2 = lane >> 5, hl = lane & 31;
    int dp = hl & 15, epair = hl >> 4, head = dp >> 2;
    unsigned dpo = (unsigned)dp << 4;               // byte offset within feat row
    const char* fb = reinterpret_cast<const char*>(feat_h);
    const char* eb = reinterpret_cast<const char*>(el);
    int n = blockIdx.x * 8 + wave * 2 + h2;   // 6250 blocks * 8 = 50000 exactly
    int e0 = rowstart[n];
    int deg = rowstart[n + 1] - e0;           // >= 1 (self loops)
    int dmax = max(deg, __shfl_xor(deg, 32, 64));
    float4 er4 = *(const float4*)&er[n * 4];
    float s = 0.f;
    float a[8] = {};
    int nch = (dmax + 31) >> 5;

    int idx0 = e0 + min(hl, deg - 1);
    int sidx_p = esrc[idx0];
    float4 el_p = *reinterpret_cast<const float4*>(eb + ((unsigned)sidx_p << 4));
    bool val_p = hl < deg;

    for (int c = 0; c < nch; c++) {
        float w0 = 0.f, w1 = 0.f, w2 = 0.f, w3 = 0.f;
        int sv = sidx_p;
        if (val_p) {
            float ex = el_p.x + er4.x, ey = el_p.y + er4.y;
            float ez = el_p.z + er4.z, ew = el_p.w + er4.w;
            ex = fmaxf(ex, 0.f) + 0.2f * fminf(ex, 0.f);
            ey = fmaxf(ey, 0.f) + 0.2f * fminf(ey, 0.f);
            ez = fmaxf(ez, 0.f) + 0.2f * fminf(ez, 0.f);
            ew = fmaxf(ew, 0.f) + 0.2f * fminf(ew, 0.f);
            w0 = __expf(ex); w1 = __expf(ey); w2 = __expf(ez); w3 = __expf(ew);
        }
        int4* wp = reinterpret_cast<int4*>(&lds[wave][h2][c & 1][hl][0]);
        wp[0] = make_int4(sv, __float_as_int(w0), sv, __float_as_int(w1));
        wp[1] = make_int4(sv, __float_as_int(w2), sv, __float_as_int(w3));
        if (c + 1 < nch) {
            int slot = (c + 1) * 32 + hl;
            int idx = e0 + min(slot, deg - 1);
            sidx_p = esrc[idx];
            el_p = *reinterpret_cast<const float4*>(eb + ((unsigned)sidx_p << 4));
            val_p = slot < deg;
        }
        int cnt = min(32, dmax - c * 32);
        int iters = (cnt + 1) >> 1;
        const int2 (*slot_p)[4] = lds[wave][h2][c & 1];
        int j = 0;
        // ---- 4-deep batch: 4 independent gathers in flight per lane ----
#pragma unroll 1
        for (; j + 4 <= iters; j += 4) {
            int2 r0 = slot_p[(j + 0) * 2 + epair][head];
            int2 r1 = slot_p[(j + 1) * 2 + epair][head];
            int2 r2 = slot_p[(j + 2) * 2 + epair][head];
            int2 r3 = slot_p[(j + 3) * 2 + epair][head];
            uint4 u0 = *reinterpret_cast<const uint4*>(fb + (((unsigned)r0.x << 8) + dpo));
            uint4 u1 = *reinterpret_cast<const uint4*>(fb + (((unsigned)r1.x << 8) + dpo));
            uint4 u2 = *reinterpret_cast<const uint4*>(fb + (((unsigned)r2.x << 8) + dpo));
            uint4 u3 = *reinterpret_cast<const uint4*>(fb + (((unsigned)r3.x << 8) + dpo));
            float wa = __int_as_float(r0.y), wb = __int_as_float(r1.y);
            float wc = __int_as_float(r2.y), wd = __int_as_float(r3.y);
            FMAMIX_LO(a[0], u0.x, wa); FMAMIX_HI(a[1], u0.x, wa);
            FMAMIX_LO(a[2], u0.y, wa); FMAMIX_HI(a[3], u0.y, wa);
            FMAMIX_LO(a[4], u0.z, wa); FMAMIX_HI(a[5], u0.z, wa);
            FMAMIX_LO(a[6], u0.w, wa); FMAMIX_HI(a[7], u0.w, wa);
            FMAMIX_LO(a[0], u1.x, wb); FMAMIX_HI(a[1], u1.x, wb);
            FMAMIX_LO(a[2], u1.y, wb); FMAMIX_HI(a[3], u1.y, wb);
            FMAMIX_LO(a[4], u1.z, wb); FMAMIX_HI(a[5], u1.z, wb);
            FMAMIX_LO(a[6], u1.w, wb); FMAMIX_HI(a[7], u1.w, wb);
            FMAMIX_LO(a[0], u2.x, wc); FMAMIX_HI(a[1], u2.x, wc);
            FMAMIX_LO(a[2], u2.y, wc); FMAMIX_HI(a[3], u2.y, wc);
            FMAMIX_LO(a[4], u2.z, wc); FMAMIX_HI(a[5], u2.z, wc);
            FMAMIX_LO(a[6], u2.w, wc); FMAMIX_HI(a[7], u2.w, wc);
            FMAMIX_LO(a[0], u3.x, wd); FMAMIX_HI(a[1], u3.x, wd);
            FMAMIX_LO(a[2], u3.y, wd); FMAMIX_HI(a[3], u3.y, wd);
            FMAMIX_LO(a[4], u3.z, wd); FMAMIX_HI(a[5], u3.z, wd);
            FMAMIX_LO(a[6], u3.w, wd); FMAMIX_HI(a[7], u3.w, wd);
            s += (wa + wb) + (wc + wd);
        }
#pragma unroll 1
        for (; j < iters; j++) {
            int2 rec = slot_p[j * 2 + epair][head];
            float w = __int_as_float(rec.y);
            uint4 u = *reinterpret_cast<const uint4*>(fb + (((unsigned)rec.x << 8) + dpo));
            FMAMIX_LO(a[0], u.x, w); FMAMIX_HI(a[1], u.x, w);
            FMAMIX_LO(a[2], u.y, w); FMAMIX_HI(a[3], u.y, w);
            FMAMIX_LO(a[4], u.z, w); FMAMIX_HI(a[5], u.z, w);
            FMAMIX_LO(a[6], u.w, w); FMAMIX_HI(a[7], u.w, w);
            s += w;
        }
    }
#pragma unroll
    for (int k = 0; k < 8; k++) a[k] += __shfl_xor(a[k], 16, 64);
    s += __shfl_xor(s, 16, 64);
    float r[8] = {};
    if (epair == 0) {
        float inv = 1.f / s;
        int d0 = dp * 8;
#pragma unroll
        for (int k = 0; k < 8; k++) r[k] = a[k] * inv;
        if (layer > 0) {
            float4 hraw = *reinterpret_cast<const float4*>(&h[(size_t)n * HDIM + d0]);
            __half2 q0 = *(__half2*)&hraw.x, q1 = *(__half2*)&hraw.y;
            __half2 q2 = *(__half2*)&hraw.z, q3 = *(__half2*)&hraw.w;
            float hv[8] = {__half2float(__low2half(q0)), __half2float(__high2half(q0)),
                           __half2float(__low2half(q1)), __half2float(__high2half(q1)),
                           __half2float(__low2half(q2)), __half2float(__high2half(q2)),
                           __half2float(__low2half(q3)), __half2float(__high2half(q3))};
            float4 sc0 = *reinterpret_cast<const float4*>(&s_sc[d0]);
            float4 sc1 = *reinterpret_cast<const float4*>(&s_sc[d0 + 4]);
            float4 sh0 = *reinterpret_cast<const float4*>(&s_sh[d0]);
            float4 sh1 = *reinterpret_cast<const float4*>(&s_sh[d0 + 4]);
            float scv[8] = {sc0.x, sc0.y, sc0.z, sc0.w, sc1.x, sc1.y, sc1.z, sc1.w};
            float shv[8] = {sh0.x, sh0.y, sh0.z, sh0.w, sh1.x, sh1.y, sh1.z, sh1.w};
#pragma unroll
            for (int k = 0; k < 8; k++) {
                float t = hv[k] * scv[k] + shv[k];
                r[k] += elu1(t);
                r[k] = elu1(r[k]);
            }
        }
        float sn = snorm_n[n];
#pragma unroll
        for (int k = 0; k < 8; k++) r[k] *= sn;
        float4 outv;
        *(__half2*)&outv.x = __floats2half2_rn(r[0], r[1]);
        *(__half2*)&outv.y = __floats2half2_rn(r[2], r[3]);
        *(__half2*)&outv.z = __floats2half2_rn(r[4], r[5]);
        *(__half2*)&outv.w = __floats2half2_rn(r[6], r[7]);
        *reinterpret_cast<float4*>(&h[(size_t)n * HDIM + d0]) = outv;
    }

    // ---- BN partials: per-block LDS reduce + one atomicAdd per (c,which); NO fences ----
    float* bsum = reinterpret_cast<float*>(lds);   // 2048 floats used (of 4096)
    __syncthreads();          // all waves done with their lds hot-loop regions
    if (epair == 0) {
        int n8 = wave * 2 + h2;
        int cbase = n8 * 128 + dp * 8;
#pragma unroll
        for (int k = 0; k < 8; k++) {
            bsum[cbase + k] = r[k];
            bsum[1024 + cbase + k] = r[k] * r[k];
        }
    }
    __syncthreads();
    {
        int c = tid & 127, which = tid >> 7;   // which: 0=sum, 1=sumsq
        float v = 0.f;
#pragma unroll
        for (int n8 = 0; n8 < 8; n8++) v += bsum[which * 1024 + n8 * 128 + c];
        atomicAdd(&bn_cur[(blockIdx.x & (BN_BUCKETS - 1)) * 256 + which * 128 + c], v);
    }
}

// ---------------- classifier (h fp16), BN finalize fused ----------------
__global__ void k_classifier(const __half* __restrict__ h, const float* __restrict__ W1,
                             const float* __restrict__ b1, const float* __restrict__ W2,
                             const float* __restrict__ b2, const float* __restrict__ bn_prev,
                             const float* __restrict__ gamma, const float* __restrict__ beta,
                             float* __restrict__ out) {
    __shared__ float hs[16][128];
    __shared__ __align__(16) float s_sc[128];
    __shared__ __align__(16) float s_sh[128];
    int tid = threadIdx.x;
    {
        float* red = &hs[0][0];   // alias; hs written after
        int c = tid & 127, which = tid >> 7;
        float t = 0.f;
#pragma unroll
        for (int b = 0; b < BN_BUCKETS; b++) t += bn_prev[b * 256 + which * 128 + c];
        red[tid] = t;
        __syncthreads();
        if (tid < 128) {
            float mu = red[tid] * (1.f / N_NODES);
            float var = red[128 + tid] * (1.f / N_NODES) - mu * mu;
            float sc = gamma[tid] * rsqrtf(var + 1e-5f);
            s_sc[tid] = sc;
            s_sh[tid] = beta[tid] - mu * sc;
        }
        __syncthreads();
    }
    int nbase = blockIdx.x * 16;
    for (int i = tid; i < 16 * 128; i += 256) {
        int r = i >> 7, c = i & 127;
        int n = nbase + r;
        float v = 0.f;
        if (n < N_NODES) {
            v = __half2float(h[(size_t)n * HDIM + c]) * s_sc[c] + s_sh[c];
            v = elu1(v);
        }
        hs[r][c] = v;
    }
    __syncthreads();
    int j = tid & 63;
    int g = tid >> 6;
    float bj = b1[j];
    float acc[4] = {bj, bj, bj, bj};
    for (int k = 0; k < 128; k++) {
        float w = W1[k * 64 + j];
#pragma unroll
        for (int i = 0; i < 4; i++) acc[i] += hs[g * 4 + i][k] * w;
    }
    float w20 = W2[j * 2], w21 = W2[j * 2 + 1];
    float res[8];
#pragma unroll
    for (int i = 0; i < 4; i++) {
        float hid = fmaxf(acc[i], 0.f);
        res[2 * i] = hid * w20;
        res[2 * i + 1] = hid * w21;
    }
#pragma unroll
    for (int off = 1; off < 64; off <<= 1)
#pragma unroll
        for (int i = 0; i < 8; i++) res[i] += __shfl_xor(res[i], off, 64);
    if (j < 8) {
        int n = nbase + g * 4 + (j >> 1);
        if (n < N_NODES) out[n * 2 + (j & 1)] = res[j] + b2[j & 1];
    }
}

// ----------------------------------------------------------------
extern "C" void kernel_launch(void* const* d_in, const int* in_sizes, int n_in,
                              void* d_out, int out_size, void* d_ws, size_t ws_size,
                              hipStream_t stream) {
    const int* x = (const int*)d_in[0];
    const int* src = (const int*)d_in[1];
    const int* dst = (const int*)d_in[2];
    const float* snorm_n = (const float*)d_in[3];
    const float* embed = (const float*)d_in[5];
    const float* Ws[3] = {(const float*)d_in[6], (const float*)d_in[11], (const float*)d_in[16]};
    const float* als[3] = {(const float*)d_in[7], (const float*)d_in[12], (const float*)d_in[17]};
    const float* ars[3] = {(const float*)d_in[8], (const float*)d_in[13], (const float*)d_in[18]};
    const float* gms[3] = {(const float*)d_in[9], (const float*)d_in[14], (const float*)d_in[19]};
    const float* bts[3] = {(const float*)d_in[10], (const float*)d_in[15], (const float*)d_in[20]};
    const float* cls1_w = (const float*)d_in[21];
    const float* cls1_b = (const float*)d_in[22];
    const float* cls2_w = (const float*)d_in[23];
    const float* cls2_b = (const float*)d_in[24];
    float* out = (float*)d_out;

    char* ws = (char*)d_ws;
    size_t off = 0;
    auto alloc = [&](size_t bytes) {
        void* p = ws + off;
        off = (off + bytes + 255) & ~(size_t)255;
        return p;
    };
    __half* h = (__half*)alloc((size_t)N_NODES * HDIM * 2);
    __half* feat_h = (__half*)alloc((size_t)N_NODES * HDIM * 2);
    float* el = (float*)alloc((size_t)N_NODES * 4 * 4);
    float* er = (float*)alloc((size_t)N_NODES * 4 * 4);
    int* rowstart = (int*)alloc((size_t)(N_NODES + 1) * 4);
    int* esrc = (int*)alloc((size_t)N_EDGES * 4);
    int* g_cursor = (int*)alloc((size_t)NB2 * 4);
    float* bn_part = (float*)alloc((size_t)3 * BN_BUCKETS * 256 * 4);
    __half* wpkh = (__half*)alloc((size_t)3 * 16384 * 2);
    unsigned* g_bucket = (unsigned*)feat_h;  // 4 MB alias; CSR build finishes before gemm
    (void)ws_size; (void)in_sizes; (void)n_in; (void)out_size;

    k_wpack<<<(3 * 2048 + 255) / 256, 256, 0, stream>>>(Ws[0], Ws[1], Ws[2], wpkh,
                                                        bn_part, g_cursor);
    k_partA<<<GA, 1024, 0, stream>>>(src, dst, g_cursor, g_bucket);
    k_partB<<<NB2, 1024, 0, stream>>>(g_bucket, g_cursor, rowstart, esrc);

    for (int L = 0; L < 3; L++) {
        const f16x8* wB = reinterpret_cast<const f16x8*>(wpkh + ((size_t)L << 14));
        const float* bn_prev = bn_part + (size_t)(L == 0 ? 0 : L - 1) * BN_BUCKETS * 256;
        float* bn_cur = bn_part + (size_t)L * BN_BUCKETS * 256;
        int gprev = (L == 0) ? 0 : L - 1;
        k_gemm6<<<(N_NODES + 63) / 64, 256, 0, stream>>>(h, x, embed, wB, feat_h,
                                                         bn_prev, gms[gprev], bts[gprev],
                                                         als[L], ars[L], el, er, L == 0 ? 0 : 1);
        k_agg12<<<AGG_BLOCKS, 256, 0, stream>>>(feat_h, el, er, rowstart, esrc,
                                                snorm_n, h, bn_prev, gms[gprev], bts[gprev],
                                                bn_cur, L);
    }

    k_classifier<<<(N_NODES + 15) / 16, 256, 0, stream>>>(h, cls1_w, cls1_b, cls2_w, cls2_b,
                                                          bn_part + (size_t)2 * BN_BUCKETS * 256,
                                                          gms[2], bts[2], out);
}

// Round 7
// 310.628 us; speedup vs baseline: 1.1120x; 1.0652x over previous
//
#include <hip/hip_runtime.h>
#include <hip/hip_bf16.h>
#include <hip/hip_fp16.h>
#include <math.h>

constexpr int N_NODES = 50000;
constexpr int N_EDGES = 850000;
constexpr int HDIM = 128;   // H*D
constexpr int AGG_BLOCKS = N_NODES / 8;  // 6250
constexpr int BN_BUCKETS = 16;

typedef _Float16 f16x8 __attribute__((ext_vector_type(8)));
typedef float f32x4 __attribute__((ext_vector_type(4)));

// v_fma_mix_f32: acc += f16(lo/hi of pk) * w   (exact f16->f32 convert inside FMA)
#define FMAMIX_LO(acc, pk, w) \
    asm("v_fma_mix_f32 %0, %1, %2, %0 op_sel:[0,0,0] op_sel_hi:[1,0,0]" \
        : "+v"(acc) : "v"(pk), "v"(w))
#define FMAMIX_HI(acc, pk, w) \
    asm("v_fma_mix_f32 %0, %1, %2, %0 op_sel:[1,0,0] op_sel_hi:[1,0,0]" \
        : "+v"(acc) : "v"(pk), "v"(w))

__device__ __forceinline__ float elu1(float t) {
    return (t > 0.f) ? t : (__expf(t) - 1.f);
}

// ---------------- CSR build params ----------------
constexpr int NB2 = 128;                                // buckets
constexpr int RANGE2 = (N_NODES + NB2 - 1) / NB2;       // 391 nodes/bucket
constexpr int CAP = 8192;                               // bucket capacity (avg 6641)
constexpr int CHUNK = 8192;                             // edges per phase-A block
constexpr int GA = (N_EDGES + CHUNK - 1) / CHUNK;       // 104 blocks
constexpr int WPACK_BLOCKS = 6;                          // 6*1024 = 6144 = 3*2048
constexpr int GEMM0_BLOCKS = (N_NODES + 255) / 256;      // 196
constexpr int FUSEB_BLOCKS = GEMM0_BLOCKS + NB2;         // 324

// ---------------- fused dispatch A: partA (CSR phase 1) || wpack ----------------
__global__ void k_fuseA(const int* __restrict__ src, const int* __restrict__ dst,
                        int* __restrict__ g_cursor, unsigned* __restrict__ bucket,
                        const float* __restrict__ W0, const float* __restrict__ W1,
                        const float* __restrict__ W2, __half* __restrict__ wpk,
                        float* __restrict__ bn_part) {
    __shared__ int hist[NB2];
    int tid = threadIdx.x;
    if (blockIdx.x < GA) {
        // ---- partA: bucket edges by dst range ----
        int e0 = blockIdx.x * CHUNK;
        int e1 = min(e0 + CHUNK, N_EDGES);
        if (tid < NB2) hist[tid] = 0;
        __syncthreads();
        for (int i = e0 + tid; i < e1; i += 1024) {
            int d = dst[i];
            atomicAdd(&hist[d / RANGE2], 1);
        }
        __syncthreads();
        int base = 0;
        if (tid < NB2) base = atomicAdd(&g_cursor[tid], hist[tid]);
        __syncthreads();
        if (tid < NB2) hist[tid] = base;
        __syncthreads();
        for (int i = e0 + tid; i < e1; i += 1024) {
            int d = dst[i];
            int s = src[i];
            int b = d / RANGE2;
            int p = atomicAdd(&hist[b], 1);
            bucket[b * CAP + p] = (unsigned)s | ((unsigned)(d - b * RANGE2) << 16);
        }
    } else {
        // ---- wpack: W -> MFMA B-fragment layout; zero bn_part ----
        int gid = (blockIdx.x - GA) * 1024 + tid;  // [0, 6144)
        int z0 = gid * 8;
        if (z0 < 3 * BN_BUCKETS * 256) {
            float4 z = make_float4(0.f, 0.f, 0.f, 0.f);
            *reinterpret_cast<float4*>(&bn_part[z0]) = z;
            *reinterpret_cast<float4*>(&bn_part[z0 + 4]) = z;
        }
        if (gid >= 3 * 2048) return;
        int L = gid >> 11;
        int rem = gid & 2047;
        int ct = rem >> 8;
        int kc = (rem >> 6) & 3;
        int l = rem & 63;
        const float* W = (L == 0) ? W0 : ((L == 1) ? W1 : W2);
        int c = ct * 16 + (l & 15);
        int k0 = kc * 32 + (l >> 4) * 8;
        __half tmp[8];
#pragma unroll
        for (int j = 0; j < 8; j++) tmp[j] = __float2half(W[(k0 + j) * HDIM + c]);
        *reinterpret_cast<float4*>(&wpk[((size_t)L << 14) +
                                        ((size_t)(ct * 4 + kc) * 64 + l) * 8]) =
            *reinterpret_cast<float4*>(tmp);
    }
}

// ---------------- fused dispatch B: gemm layer-0 (mode0, 256 nodes/block) || partB ----------------
__global__ void k_fuseB(const int* __restrict__ xidx, const float* __restrict__ embed,
                        const f16x8* __restrict__ wB, __half* __restrict__ feat_h,
                        const float* __restrict__ al, const float* __restrict__ ar,
                        float* __restrict__ el, float* __restrict__ er,
                        const unsigned* __restrict__ bucket, const int* __restrict__ cnts,
                        int* __restrict__ rowstart, int* __restrict__ esrc) {
    __shared__ __align__(16) char smem[16 * 16 * 136 * 2];  // 69.6 KB, aliased per branch
    int tid = threadIdx.x;
    if (blockIdx.x < GEMM0_BLOCKS) {
        // ---- gemm0: feat = embed[x] @ W0 (MFMA), fused el/er; 16 waves, 256 nodes ----
        __half (*sf)[16][136] = reinterpret_cast<__half (*)[16][136]>(smem);
        int w = tid >> 6, lane = tid & 63;
        int r = lane & 15, kg = lane >> 4;
        int wbase = blockIdx.x * 256 + w * 16;
        int n = wbase + r;
        bool ok = n < N_NODES;
        f16x8 aF[4];
#pragma unroll
        for (int kc = 0; kc < 4; kc++)
#pragma unroll
            for (int j = 0; j < 8; j++) aF[kc][j] = (_Float16)0.f;
        if (ok) {
            int xi = xidx[n];
            const float* ep = embed + (size_t)xi * HDIM;
#pragma unroll
            for (int kc = 0; kc < 4; kc++) {
                int c0 = kc * 32 + kg * 8;
                float4 e0 = *reinterpret_cast<const float4*>(ep + c0);
                float4 e1 = *reinterpret_cast<const float4*>(ep + c0 + 4);
                aF[kc][0] = (_Float16)e0.x; aF[kc][1] = (_Float16)e0.y;
                aF[kc][2] = (_Float16)e0.z; aF[kc][3] = (_Float16)e0.w;
                aF[kc][4] = (_Float16)e1.x; aF[kc][5] = (_Float16)e1.y;
                aF[kc][6] = (_Float16)e1.z; aF[kc][7] = (_Float16)e1.w;
            }
        }
        f32x4 acc[8] = {};
#pragma unroll
        for (int kc = 0; kc < 4; kc++) {
#pragma unroll
            for (int ct = 0; ct < 8; ct++) {
                f16x8 bF = wB[(ct * 4 + kc) * 64 + lane];
                acc[ct] = __builtin_amdgcn_mfma_f32_16x16x32_f16(aF[kc], bF, acc[ct], 0, 0, 0);
            }
        }
#pragma unroll
        for (int ct = 0; ct < 8; ct++)
#pragma unroll
            for (int reg = 0; reg < 4; reg++)
                sf[w][kg * 4 + reg][ct * 16 + r] = __float2half(acc[ct][reg]);
        __syncthreads();
        float alq[8], arq[8];
        {
            float4 a0 = *reinterpret_cast<const float4*>(&al[r * 8]);
            float4 a1 = *reinterpret_cast<const float4*>(&al[r * 8 + 4]);
            float4 b0 = *reinterpret_cast<const float4*>(&ar[r * 8]);
            float4 b1 = *reinterpret_cast<const float4*>(&ar[r * 8 + 4]);
            alq[0] = a0.x; alq[1] = a0.y; alq[2] = a0.z; alq[3] = a0.w;
            alq[4] = a1.x; alq[5] = a1.y; alq[6] = a1.z; alq[7] = a1.w;
            arq[0] = b0.x; arq[1] = b0.y; arq[2] = b0.z; arq[3] = b0.w;
            arq[4] = b1.x; arq[5] = b1.y; arq[6] = b1.z; arq[7] = b1.w;
        }
#pragma unroll
        for (int q = 0; q < 4; q++) {
            int row = q * 4 + kg;
            int n2 = wbase + row;
            float4 v = *reinterpret_cast<const float4*>(&sf[w][row][r * 8]);
            if (n2 < N_NODES)
                *reinterpret_cast<float4*>(&feat_h[(size_t)n2 * HDIM + r * 8]) = v;
            const __half2* u = reinterpret_cast<const __half2*>(&v);
            float pl = 0.f, pr = 0.f;
#pragma unroll
            for (int t = 0; t < 4; t++) {
                float lo = __half2float(__low2half(u[t]));
                float hi = __half2float(__high2half(u[t]));
                pl += lo * alq[2 * t] + hi * alq[2 * t + 1];
                pr += lo * arq[2 * t] + hi * arq[2 * t + 1];
            }
            pl += __shfl_xor(pl, 1, 64); pr += __shfl_xor(pr, 1, 64);
            pl += __shfl_xor(pl, 2, 64); pr += __shfl_xor(pr, 2, 64);
            if ((r & 3) == 0 && n2 < N_NODES) {
                int head = r >> 2;
                el[n2 * 4 + head] = pl;
                er[n2 * 4 + head] = pr;
            }
        }
    } else {
        // ---- partB: per-bucket counting sort -> rowstart/esrc ----
        int* cnt_s = reinterpret_cast<int*>(smem);            // 128
        int* hist = cnt_s + NB2;                               // 391
        int* lcur = hist + RANGE2;                             // 391
        int* wsum = lcur + RANGE2;                             // 7
        int b = blockIdx.x - GEMM0_BLOCKS;
        int lo = b * RANGE2;
        int myCount = cnts[b];
        if (tid < NB2) cnt_s[tid] = cnts[tid];
        __syncthreads();
        for (int off = 1; off < NB2; off <<= 1) {
            int t = (tid < NB2 && tid >= off) ? cnt_s[tid - off] : 0;
            __syncthreads();
            if (tid < NB2) cnt_s[tid] += t;
            __syncthreads();
        }
        int base = cnt_s[b] - myCount;
        for (int j = tid; j < RANGE2; j += 1024) hist[j] = 0;
        __syncthreads();
        const unsigned* my = bucket + (size_t)b * CAP;
        for (int i = tid; i < myCount; i += 1024) atomicAdd(&hist[my[i] >> 16], 1);
        __syncthreads();
        int v = 0;
        if (tid < 448) v = (tid < RANGE2) ? hist[tid] : 0;
        int inc = v;
        int lane = tid & 63;
#pragma unroll
        for (int off = 1; off < 64; off <<= 1) {
            int t = __shfl_up(inc, off, 64);
            if (lane >= off) inc += t;
        }
        if (tid < 448 && lane == 63) wsum[tid >> 6] = inc;
        __syncthreads();
        if (tid < RANGE2) {
            int woff = 0;
            for (int w = 0; w < (tid >> 6); w++) woff += wsum[w];
            int excl = woff + inc - v;
            lcur[tid] = excl;
            int node = lo + tid;
            if (node < N_NODES) rowstart[node] = base + excl;
        }
        if (b == 0 && tid == 0) rowstart[N_NODES] = N_EDGES;
        __syncthreads();
        for (int i = tid; i < myCount; i += 1024) {
            unsigned p = my[i];
            int pos = atomicAdd(&lcur[p >> 16], 1);
            esrc[base + pos] = (int)(p & 0xFFFFu);
        }
    }
}

// ---------------- GEMM v6: MFMA 16x16x32_f16, BN finalize fused in prologue (L1/L2) ----------------
__global__ void k_gemm6(const __half* __restrict__ h, const f16x8* __restrict__ wB,
                        __half* __restrict__ feat_h, const float* __restrict__ bn_prev,
                        const float* __restrict__ gamma, const float* __restrict__ beta,
                        const float* __restrict__ al, const float* __restrict__ ar,
                        float* __restrict__ el, float* __restrict__ er) {
    __shared__ __half sf[4][16][136];  // per-wave 16x128 fp16 tile (+8 pad), 17.4 KB
    __shared__ __align__(16) float s_sc[128];
    __shared__ __align__(16) float s_sh[128];
    int tid = threadIdx.x;
    // ---- BN finalize prologue (redundant per block; bn_prev is L2-resident 16 KB) ----
    {
        float* red = reinterpret_cast<float*>(sf);   // alias; sf written after
        int c = tid & 127, which = tid >> 7;
        float t = 0.f;
#pragma unroll
        for (int b = 0; b < BN_BUCKETS; b++) t += bn_prev[b * 256 + which * 128 + c];
        red[tid] = t;
        __syncthreads();
        if (tid < 128) {
            float mu = red[tid] * (1.f / N_NODES);
            float var = red[128 + tid] * (1.f / N_NODES) - mu * mu;
            float sc = gamma[tid] * rsqrtf(var + 1e-5f);
            s_sc[tid] = sc;
            s_sh[tid] = beta[tid] - mu * sc;
        }
        __syncthreads();
    }
    int w = tid >> 6, lane = tid & 63;
    int r = lane & 15, kg = lane >> 4;
    int wbase = blockIdx.x * 64 + w * 16;
    int n = wbase + r;
    bool ok = n < N_NODES;

    f16x8 aF[4];
#pragma unroll
    for (int kc = 0; kc < 4; kc++)
#pragma unroll
        for (int j = 0; j < 8; j++) aF[kc][j] = (_Float16)0.f;
    if (ok) {
        const __half* hp = h + (size_t)n * HDIM;
#pragma unroll
        for (int kc = 0; kc < 4; kc++) {
            int c0 = kc * 32 + kg * 8;
            float4 raw = *reinterpret_cast<const float4*>(hp + c0);
            const __half2* u = reinterpret_cast<const __half2*>(&raw);
            float4 sc0 = *reinterpret_cast<const float4*>(&s_sc[c0]);
            float4 sc1 = *reinterpret_cast<const float4*>(&s_sc[c0 + 4]);
            float4 sh0 = *reinterpret_cast<const float4*>(&s_sh[c0]);
            float4 sh1 = *reinterpret_cast<const float4*>(&s_sh[c0 + 4]);
            float scv[8] = {sc0.x, sc0.y, sc0.z, sc0.w, sc1.x, sc1.y, sc1.z, sc1.w};
            float shv[8] = {sh0.x, sh0.y, sh0.z, sh0.w, sh1.x, sh1.y, sh1.z, sh1.w};
            float vv[8];
#pragma unroll
            for (int t = 0; t < 4; t++) {
                vv[2 * t] = __half2float(__low2half(u[t]));
                vv[2 * t + 1] = __half2float(__high2half(u[t]));
            }
#pragma unroll
            for (int j = 0; j < 8; j++) {
                float t = vv[j] * scv[j] + shv[j];
                aF[kc][j] = (_Float16)elu1(t);
            }
        }
    }
    __syncthreads();  // red alias done before sf writes

    f32x4 acc[8] = {};
#pragma unroll
    for (int kc = 0; kc < 4; kc++) {
#pragma unroll
        for (int ct = 0; ct < 8; ct++) {
            f16x8 bF = wB[(ct * 4 + kc) * 64 + lane];
            acc[ct] = __builtin_amdgcn_mfma_f32_16x16x32_f16(aF[kc], bF, acc[ct], 0, 0, 0);
        }
    }

#pragma unroll
    for (int ct = 0; ct < 8; ct++)
#pragma unroll
        for (int reg = 0; reg < 4; reg++)
            sf[w][kg * 4 + reg][ct * 16 + r] = __float2half(acc[ct][reg]);
    __syncthreads();
    float alq[8], arq[8];
    {
        float4 a0 = *reinterpret_cast<const float4*>(&al[r * 8]);
        float4 a1 = *reinterpret_cast<const float4*>(&al[r * 8 + 4]);
        float4 b0 = *reinterpret_cast<const float4*>(&ar[r * 8]);
        float4 b1 = *reinterpret_cast<const float4*>(&ar[r * 8 + 4]);
        alq[0] = a0.x; alq[1] = a0.y; alq[2] = a0.z; alq[3] = a0.w;
        alq[4] = a1.x; alq[5] = a1.y; alq[6] = a1.z; alq[7] = a1.w;
        arq[0] = b0.x; arq[1] = b0.y; arq[2] = b0.z; arq[3] = b0.w;
        arq[4] = b1.x; arq[5] = b1.y; arq[6] = b1.z; arq[7] = b1.w;
    }
#pragma unroll
    for (int q = 0; q < 4; q++) {
        int row = q * 4 + kg;
        int n2 = wbase + row;
        float4 v = *reinterpret_cast<const float4*>(&sf[w][row][r * 8]);
        if (n2 < N_NODES)
            *reinterpret_cast<float4*>(&feat_h[(size_t)n2 * HDIM + r * 8]) = v;
        const __half2* u = reinterpret_cast<const __half2*>(&v);
        float pl = 0.f, pr = 0.f;
#pragma unroll
        for (int t = 0; t < 4; t++) {
            float lo = __half2float(__low2half(u[t]));
            float hi = __half2float(__high2half(u[t]));
            pl += lo * alq[2 * t] + hi * alq[2 * t + 1];
            pr += lo * arq[2 * t] + hi * arq[2 * t + 1];
        }
        pl += __shfl_xor(pl, 1, 64); pr += __shfl_xor(pr, 1, 64);
        pl += __shfl_xor(pl, 2, 64); pr += __shfl_xor(pr, 2, 64);
        if ((r & 3) == 0 && n2 < N_NODES) {
            int head = r >> 2;
            el[n2 * 4 + head] = pl;
            er[n2 * 4 + head] = pr;
        }
    }
}

// ---------------- aggregation v12: 4-deep gather pipeline (MLP), fma_mix consume ----------------
__global__ void k_agg12(const __half* __restrict__ feat_h, const float* __restrict__ el,
                        const float* __restrict__ er, const int* __restrict__ rowstart,
                        const int* __restrict__ esrc, const float* __restrict__ snorm_n,
                        __half* __restrict__ h, const float* __restrict__ bn_prev,
                        const float* __restrict__ gamma, const float* __restrict__ beta,
                        float* __restrict__ bn_cur, int layer) {
    __shared__ __align__(16) int2 lds[4][2][2][32][4];  // [wave][h2][buf][slot][head], 16 KB
    __shared__ __align__(16) float s_sc[128];
    __shared__ __align__(16) float s_sh[128];
    int tid = threadIdx.x;
    if (layer > 0) {
        float* red = reinterpret_cast<float*>(lds);  // alias; lds rewritten after barrier
        int c = tid & 127, which = tid >> 7;
        float t = 0.f;
#pragma unroll
        for (int b = 0; b < BN_BUCKETS; b++) t += bn_prev[b * 256 + which * 128 + c];
        red[tid] = t;
        __syncthreads();
        if (tid < 128) {
            float mu = red[tid] * (1.f / N_NODES);
            float var = red[128 + tid] * (1.f / N_NODES) - mu * mu;
            float sc = gamma[tid] * rsqrtf(var + 1e-5f);
            s_sc[tid] = sc;
            s_sh[tid] = beta[tid] - mu * sc;
        }
        __syncthreads();
    }
    int wave = tid >> 6, lane = tid & 63;
    int h2 = lane >> 5, hl = lane & 31;
    int dp = hl & 15, epair = hl >> 4, head = dp >> 2;
    unsigned dpo = (unsigned)dp << 4;
    const char* fb = reinterpret_cast<const char*>(feat_h);
    const char* eb = reinterpret_cast<const char*>(el);
    int n = blockIdx.x * 8 + wave * 2 + h2;
    int e0 = rowstart[n];
    int deg = rowstart[n + 1] - e0;
    int dmax = max(deg, __shfl_xor(deg, 32, 64));
    float4 er4 = *(const float4*)&er[n * 4];
    float s = 0.f;
    float a[8] = {};
    int nch = (dmax + 31) >> 5;

    int idx0 = e0 + min(hl, deg - 1);
    int sidx_p = esrc[idx0];
    float4 el_p = *reinterpret_cast<const float4*>(eb + ((unsigned)sidx_p << 4));
    bool val_p = hl < deg;

    for (int c = 0; c < nch; c++) {
        float w0 = 0.f, w1 = 0.f, w2 = 0.f, w3 = 0.f;
        int sv = sidx_p;
        if (val_p) {
            float ex = el_p.x + er4.x, ey = el_p.y + er4.y;
            float ez = el_p.z + er4.z, ew = el_p.w + er4.w;
            ex = fmaxf(ex, 0.f) + 0.2f * fminf(ex, 0.f);
            ey = fmaxf(ey, 0.f) + 0.2f * fminf(ey, 0.f);
            ez = fmaxf(ez, 0.f) + 0.2f * fminf(ez, 0.f);
            ew = fmaxf(ew, 0.f) + 0.2f * fminf(ew, 0.f);
            w0 = __expf(ex); w1 = __expf(ey); w2 = __expf(ez); w3 = __expf(ew);
        }
        int4* wp = reinterpret_cast<int4*>(&lds[wave][h2][c & 1][hl][0]);
        wp[0] = make_int4(sv, __float_as_int(w0), sv, __float_as_int(w1));
        wp[1] = make_int4(sv, __float_as_int(w2), sv, __float_as_int(w3));
        if (c + 1 < nch) {
            int slot = (c + 1) * 32 + hl;
            int idx = e0 + min(slot, deg - 1);
            sidx_p = esrc[idx];
            el_p = *reinterpret_cast<const float4*>(eb + ((unsigned)sidx_p << 4));
            val_p = slot < deg;
        }
        int cnt = min(32, dmax - c * 32);
        int iters = (cnt + 1) >> 1;
        const int2 (*slot_p)[4] = lds[wave][h2][c & 1];
        int j = 0;
#pragma unroll 1
        for (; j + 4 <= iters; j += 4) {
            int2 r0 = slot_p[(j + 0) * 2 + epair][head];
            int2 r1 = slot_p[(j + 1) * 2 + epair][head];
            int2 r2 = slot_p[(j + 2) * 2 + epair][head];
            int2 r3 = slot_p[(j + 3) * 2 + epair][head];
            uint4 u0 = *reinterpret_cast<const uint4*>(fb + (((unsigned)r0.x << 8) + dpo));
            uint4 u1 = *reinterpret_cast<const uint4*>(fb + (((unsigned)r1.x << 8) + dpo));
            uint4 u2 = *reinterpret_cast<const uint4*>(fb + (((unsigned)r2.x << 8) + dpo));
            uint4 u3 = *reinterpret_cast<const uint4*>(fb + (((unsigned)r3.x << 8) + dpo));
            float wa = __int_as_float(r0.y), wb = __int_as_float(r1.y);
            float wc = __int_as_float(r2.y), wd = __int_as_float(r3.y);
            FMAMIX_LO(a[0], u0.x, wa); FMAMIX_HI(a[1], u0.x, wa);
            FMAMIX_LO(a[2], u0.y, wa); FMAMIX_HI(a[3], u0.y, wa);
            FMAMIX_LO(a[4], u0.z, wa); FMAMIX_HI(a[5], u0.z, wa);
            FMAMIX_LO(a[6], u0.w, wa); FMAMIX_HI(a[7], u0.w, wa);
            FMAMIX_LO(a[0], u1.x, wb); FMAMIX_HI(a[1], u1.x, wb);
            FMAMIX_LO(a[2], u1.y, wb); FMAMIX_HI(a[3], u1.y, wb);
            FMAMIX_LO(a[4], u1.z, wb); FMAMIX_HI(a[5], u1.z, wb);
            FMAMIX_LO(a[6], u1.w, wb); FMAMIX_HI(a[7], u1.w, wb);
            FMAMIX_LO(a[0], u2.x, wc); FMAMIX_HI(a[1], u2.x, wc);
            FMAMIX_LO(a[2], u2.y, wc); FMAMIX_HI(a[3], u2.y, wc);
            FMAMIX_LO(a[4], u2.z, wc); FMAMIX_HI(a[5], u2.z, wc);
            FMAMIX_LO(a[6], u2.w, wc); FMAMIX_HI(a[7], u2.w, wc);
            FMAMIX_LO(a[0], u3.x, wd); FMAMIX_HI(a[1], u3.x, wd);
            FMAMIX_LO(a[2], u3.y, wd); FMAMIX_HI(a[3], u3.y, wd);
            FMAMIX_LO(a[4], u3.z, wd); FMAMIX_HI(a[5], u3.z, wd);
            FMAMIX_LO(a[6], u3.w, wd); FMAMIX_HI(a[7], u3.w, wd);
            s += (wa + wb) + (wc + wd);
        }
#pragma unroll 1
        for (; j < iters; j++) {
            int2 rec = slot_p[j * 2 + epair][head];
            float w = __int_as_float(rec.y);
            uint4 u = *reinterpret_cast<const uint4*>(fb + (((unsigned)rec.x << 8) + dpo));
            FMAMIX_LO(a[0], u.x, w); FMAMIX_HI(a[1], u.x, w);
            FMAMIX_LO(a[2], u.y, w); FMAMIX_HI(a[3], u.y, w);
            FMAMIX_LO(a[4], u.z, w); FMAMIX_HI(a[5], u.z, w);
            FMAMIX_LO(a[6], u.w, w); FMAMIX_HI(a[7], u.w, w);
            s += w;
        }
    }
#pragma unroll
    for (int k = 0; k < 8; k++) a[k] += __shfl_xor(a[k], 16, 64);
    s += __shfl_xor(s, 16, 64);
    float r[8] = {};
    if (epair == 0) {
        float inv = 1.f / s;
        int d0 = dp * 8;
#pragma unroll
        for (int k = 0; k < 8; k++) r[k] = a[k] * inv;
        if (layer > 0) {
            float4 hraw = *reinterpret_cast<const float4*>(&h[(size_t)n * HDIM + d0]);
            __half2 q0 = *(__half2*)&hraw.x, q1 = *(__half2*)&hraw.y;
            __half2 q2 = *(__half2*)&hraw.z, q3 = *(__half2*)&hraw.w;
            float hv[8] = {__half2float(__low2half(q0)), __half2float(__high2half(q0)),
                           __half2float(__low2half(q1)), __half2float(__high2half(q1)),
                           __half2float(__low2half(q2)), __half2float(__high2half(q2)),
                           __half2float(__low2half(q3)), __half2float(__high2half(q3))};
            float4 sc0 = *reinterpret_cast<const float4*>(&s_sc[d0]);
            float4 sc1 = *reinterpret_cast<const float4*>(&s_sc[d0 + 4]);
            float4 sh0 = *reinterpret_cast<const float4*>(&s_sh[d0]);
            float4 sh1 = *reinterpret_cast<const float4*>(&s_sh[d0 + 4]);
            float scv[8] = {sc0.x, sc0.y, sc0.z, sc0.w, sc1.x, sc1.y, sc1.z, sc1.w};
            float shv[8] = {sh0.x, sh0.y, sh0.z, sh0.w, sh1.x, sh1.y, sh1.z, sh1.w};
#pragma unroll
            for (int k = 0; k < 8; k++) {
                float t = hv[k] * scv[k] + shv[k];
                r[k] += elu1(t);
                r[k] = elu1(r[k]);
            }
        }
        float sn = snorm_n[n];
#pragma unroll
        for (int k = 0; k < 8; k++) r[k] *= sn;
        float4 outv;
        *(__half2*)&outv.x = __floats2half2_rn(r[0], r[1]);
        *(__half2*)&outv.y = __floats2half2_rn(r[2], r[3]);
        *(__half2*)&outv.z = __floats2half2_rn(r[4], r[5]);
        *(__half2*)&outv.w = __floats2half2_rn(r[6], r[7]);
        *reinterpret_cast<float4*>(&h[(size_t)n * HDIM + d0]) = outv;
    }

    float* bsum = reinterpret_cast<float*>(lds);
    __syncthreads();
    if (epair == 0) {
        int n8 = wave * 2 + h2;
        int cbase = n8 * 128 + dp * 8;
#pragma unroll
        for (int k = 0; k < 8; k++) {
            bsum[cbase + k] = r[k];
            bsum[1024 + cbase + k] = r[k] * r[k];
        }
    }
    __syncthreads();
    {
        int c = tid & 127, which = tid >> 7;
        float v = 0.f;
#pragma unroll
        for (int n8 = 0; n8 < 8; n8++) v += bsum[which * 1024 + n8 * 128 + c];
        atomicAdd(&bn_cur[(blockIdx.x & (BN_BUCKETS - 1)) * 256 + which * 128 + c], v);
    }
}

// ---------------- classifier (h fp16), BN finalize fused ----------------
__global__ void k_classifier(const __half* __restrict__ h, const float* __restrict__ W1,
                             const float* __restrict__ b1, const float* __restrict__ W2,
                             const float* __restrict__ b2, const float* __restrict__ bn_prev,
                             const float* __restrict__ gamma, const float* __restrict__ beta,
                             float* __restrict__ out) {
    __shared__ float hs[16][128];
    __shared__ __align__(16) float s_sc[128];
    __shared__ __align__(16) float s_sh[128];
    int tid = threadIdx.x;
    {
        float* red = &hs[0][0];
        int c = tid & 127, which = tid >> 7;
        float t = 0.f;
#pragma unroll
        for (int b = 0; b < BN_BUCKETS; b++) t += bn_prev[b * 256 + which * 128 + c];
        red[tid] = t;
        __syncthreads();
        if (tid < 128) {
            float mu = red[tid] * (1.f / N_NODES);
            float var = red[128 + tid] * (1.f / N_NODES) - mu * mu;
            float sc = gamma[tid] * rsqrtf(var + 1e-5f);
            s_sc[tid] = sc;
            s_sh[tid] = beta[tid] - mu * sc;
        }
        __syncthreads();
    }
    int nbase = blockIdx.x * 16;
    for (int i = tid; i < 16 * 128; i += 256) {
        int r = i >> 7, c = i & 127;
        int n = nbase + r;
        float v = 0.f;
        if (n < N_NODES) {
            v = __half2float(h[(size_t)n * HDIM + c]) * s_sc[c] + s_sh[c];
            v = elu1(v);
        }
        hs[r][c] = v;
    }
    __syncthreads();
    int j = tid & 63;
    int g = tid >> 6;
    float bj = b1[j];
    float acc[4] = {bj, bj, bj, bj};
    for (int k = 0; k < 128; k++) {
        float w = W1[k * 64 + j];
#pragma unroll
        for (int i = 0; i < 4; i++) acc[i] += hs[g * 4 + i][k] * w;
    }
    float w20 = W2[j * 2], w21 = W2[j * 2 + 1];
    float res[8];
#pragma unroll
    for (int i = 0; i < 4; i++) {
        float hid = fmaxf(acc[i], 0.f);
        res[2 * i] = hid * w20;
        res[2 * i + 1] = hid * w21;
    }
#pragma unroll
    for (int off = 1; off < 64; off <<= 1)
#pragma unroll
        for (int i = 0; i < 8; i++) res[i] += __shfl_xor(res[i], off, 64);
    if (j < 8) {
        int n = nbase + g * 4 + (j >> 1);
        if (n < N_NODES) out[n * 2 + (j & 1)] = res[j] + b2[j & 1];
    }
}

// ----------------------------------------------------------------
extern "C" void kernel_launch(void* const* d_in, const int* in_sizes, int n_in,
                              void* d_out, int out_size, void* d_ws, size_t ws_size,
                              hipStream_t stream) {
    const int* x = (const int*)d_in[0];
    const int* src = (const int*)d_in[1];
    const int* dst = (const int*)d_in[2];
    const float* snorm_n = (const float*)d_in[3];
    const float* embed = (const float*)d_in[5];
    const float* Ws[3] = {(const float*)d_in[6], (const float*)d_in[11], (const float*)d_in[16]};
    const float* als[3] = {(const float*)d_in[7], (const float*)d_in[12], (const float*)d_in[17]};
    const float* ars[3] = {(const float*)d_in[8], (const float*)d_in[13], (const float*)d_in[18]};
    const float* gms[3] = {(const float*)d_in[9], (const float*)d_in[14], (const float*)d_in[19]};
    const float* bts[3] = {(const float*)d_in[10], (const float*)d_in[15], (const float*)d_in[20]};
    const float* cls1_w = (const float*)d_in[21];
    const float* cls1_b = (const float*)d_in[22];
    const float* cls2_w = (const float*)d_in[23];
    const float* cls2_b = (const float*)d_in[24];
    float* out = (float*)d_out;

    char* ws = (char*)d_ws;
    size_t off = 0;
    auto alloc = [&](size_t bytes) {
        void* p = ws + off;
        off = (off + bytes + 255) & ~(size_t)255;
        return p;
    };
    __half* h = (__half*)alloc((size_t)N_NODES * HDIM * 2);
    __half* feat_h = (__half*)alloc((size_t)N_NODES * HDIM * 2);
    float* el = (float*)alloc((size_t)N_NODES * 4 * 4);
    float* er = (float*)alloc((size_t)N_NODES * 4 * 4);
    int* rowstart = (int*)alloc((size_t)(N_NODES + 1) * 4);
    int* esrc = (int*)alloc((size_t)N_EDGES * 4);
    int* g_cursor = (int*)alloc((size_t)NB2 * 4);
    float* bn_part = (float*)alloc((size_t)3 * BN_BUCKETS * 256 * 4);
    __half* wpkh = (__half*)alloc((size_t)3 * 16384 * 2);
    unsigned* g_bucket = (unsigned*)alloc((size_t)NB2 * CAP * 4);  // 4 MB, NOT aliased (gemm0 || partB)
    (void)ws_size; (void)in_sizes; (void)n_in; (void)out_size;

    hipMemsetAsync(g_cursor, 0, NB2 * 4, stream);
    k_fuseA<<<GA + WPACK_BLOCKS, 1024, 0, stream>>>(src, dst, g_cursor, g_bucket,
                                                    Ws[0], Ws[1], Ws[2], wpkh, bn_part);
    k_fuseB<<<FUSEB_BLOCKS, 1024, 0, stream>>>(x, embed,
                                               reinterpret_cast<const f16x8*>(wpkh),
                                               feat_h, als[0], ars[0], el, er,
                                               g_bucket, g_cursor, rowstart, esrc);
    k_agg12<<<AGG_BLOCKS, 256, 0, stream>>>(feat_h, el, er, rowstart, esrc,
                                            snorm_n, h, bn_part, gms[0], bts[0],
                                            bn_part, 0);
    for (int L = 1; L < 3; L++) {
        const f16x8* wB = reinterpret_cast<const f16x8*>(wpkh + ((size_t)L << 14));
        const float* bn_prev = bn_part + (size_t)(L - 1) * BN_BUCKETS * 256;
        float* bn_cur = bn_part + (size_t)L * BN_BUCKETS * 256;
        k_gemm6<<<(N_NODES + 63) / 64, 256, 0, stream>>>(h, wB, feat_h,
                                                         bn_prev, gms[L - 1], bts[L - 1],
                                                         als[L], ars[L], el, er);
        k_agg12<<<AGG_BLOCKS, 256, 0, stream>>>(feat_h, el, er, rowstart, esrc,
                                                snorm_n, h, bn_prev, gms[L - 1], bts[L - 1],
                                                bn_cur, L);
    }

    k_classifier<<<(N_NODES + 15) / 16, 256, 0, stream>>>(h, cls1_w, cls1_b, cls2_w, cls2_b,
                                                          bn_part + (size_t)2 * BN_BUCKETS * 256,
                                                          gms[2], bts[2], out);
}